// Round 1
// baseline (1123.667 us; speedup 1.0000x reference)
//
#include <hip/hip_runtime.h>

#define IN_CH 4096
#define OUT_CH 4096
#define BATCH 16384

typedef __attribute__((ext_vector_type(8))) short bf16x8;
typedef __attribute__((ext_vector_type(4))) float f32x4;
typedef __attribute__((ext_vector_type(8))) unsigned short us8;
typedef __attribute__((ext_vector_type(4))) int i32x4;

__device__ __forceinline__ unsigned short f2bf(float f) {
    union { float f; unsigned int u; } v; v.f = f;
    unsigned int u = v.u;
    unsigned int r = (u + 0x7fffu + ((u >> 16) & 1u)) >> 16;  // RNE
    return (unsigned short)r;
}

// ---- init: W_bf16 = 0, idx = -1 (8 cells per thread) ----
__global__ void init_ws(unsigned short* __restrict__ W, int* __restrict__ idx) {
    size_t t = (size_t)blockIdx.x * blockDim.x + threadIdx.x;
    size_t base = t * 8;
    us8 z = {0, 0, 0, 0, 0, 0, 0, 0};
    *(us8*)(W + base) = z;
    i32x4 m = {-1, -1, -1, -1};
    *(i32x4*)(idx + base) = m;
    *(i32x4*)(idx + base + 4) = m;
}

// ---- pass 1: last-occurrence-wins resolution via atomicMax on nnz index ----
__global__ void scatter_max(const int* __restrict__ rows, const int* __restrict__ cols,
                            int* __restrict__ idx, int nnz) {
    int i = blockIdx.x * blockDim.x + threadIdx.x;
    if (i < nnz) {
        atomicMax(&idx[(size_t)rows[i] * IN_CH + cols[i]], i);
    }
}

// ---- pass 2: winner writes its (bf16) weight ----
__global__ void scatter_write(const int* __restrict__ rows, const int* __restrict__ cols,
                              const float* __restrict__ w, const int* __restrict__ idx,
                              unsigned short* __restrict__ W, int nnz) {
    int i = blockIdx.x * blockDim.x + threadIdx.x;
    if (i < nnz) {
        size_t cell = (size_t)rows[i] * IN_CH + cols[i];
        if (idx[cell] == i) W[cell] = f2bf(w[i]);
    }
}

// ---- x f32 -> bf16, 8 elems/thread ----
__global__ void convert_x(const float* __restrict__ x, unsigned short* __restrict__ xb) {
    size_t i = ((size_t)blockIdx.x * blockDim.x + threadIdx.x) * 8;
    float4 f0 = *(const float4*)(x + i);
    float4 f1 = *(const float4*)(x + i + 4);
    us8 o;
    o[0] = f2bf(f0.x); o[1] = f2bf(f0.y); o[2] = f2bf(f0.z); o[3] = f2bf(f0.w);
    o[4] = f2bf(f1.x); o[5] = f2bf(f1.y); o[6] = f2bf(f1.z); o[7] = f2bf(f1.w);
    *(us8*)(xb + i) = o;
}

__device__ __forceinline__ void gl_lds16(const unsigned short* g, unsigned short* l) {
    __builtin_amdgcn_global_load_lds(
        (const __attribute__((address_space(1))) unsigned int*)g,
        (__attribute__((address_space(3))) unsigned int*)l,
        16, 0, 0);
}

// ---- C[M,N] = A[M,K] * B[N,K]^T + bias ; 128x128 block tile, BK=32,
//      4 waves in 2x2, each wave 4x4 grid of 16x16x32 MFMA ----
__global__ __launch_bounds__(256) void gemm_bt(
    const unsigned short* __restrict__ A,   // x_bf16 [BATCH][IN_CH]
    const unsigned short* __restrict__ B,   // W_bf16 [OUT_CH][IN_CH]
    const float* __restrict__ bias,         // [OUT_CH]
    float* __restrict__ C)                  // [BATCH][OUT_CH]
{
    __shared__ unsigned short lds[8192];    // A tile: [0,4096) elems; B tile: [4096,8192)
    const int tid  = threadIdx.x;
    const int wave = tid >> 6;
    const int lane = tid & 63;
    const int bm = blockIdx.x >> 5;         // 0..127  (M/128)
    const int bn = blockIdx.x & 31;         // 0..31   (N/128)
    const int wm = wave & 1;
    const int wn = wave >> 1;
    const int ml   = lane & 15;             // m (A) / n (B) within 16
    const int quad = lane >> 4;             // 0..3
    const int srow = lane >> 2;             // staging: row within 16-row segment
    const int scol = (lane & 3) * 8;        // staging: element offset (16 B = 8 bf16)

    // each wave stages 2 A-segments + 2 B-segments of 16 rows x 32 k
    const int seg0 = wave * 2;
    const unsigned short* ga0 = A + (size_t)(bm * 128 + seg0 * 16 + srow) * IN_CH + scol;
    const unsigned short* ga1 = ga0 + 16 * IN_CH;
    const unsigned short* gb0 = B + (size_t)(bn * 128 + seg0 * 16 + srow) * IN_CH + scol;
    const unsigned short* gb1 = gb0 + 16 * IN_CH;
    unsigned short* la0 = lds + seg0 * 512;
    unsigned short* la1 = la0 + 512;
    unsigned short* lb0 = lds + 4096 + seg0 * 512;
    unsigned short* lb1 = lb0 + 512;

    f32x4 acc[4][4];
#pragma unroll
    for (int i = 0; i < 4; ++i)
#pragma unroll
        for (int j = 0; j < 4; ++j) acc[i][j] = (f32x4){0.f, 0.f, 0.f, 0.f};

    const unsigned short* ldsA = lds;
    const unsigned short* ldsB = lds + 4096;

    for (int kt = 0; kt < IN_CH / 32; ++kt) {
        gl_lds16(ga0, la0);
        gl_lds16(ga1, la1);
        gl_lds16(gb0, lb0);
        gl_lds16(gb1, lb1);
        __syncthreads();   // drains vmcnt -> LDS writes visible

        bf16x8 af[4], bf[4];
#pragma unroll
        for (int mt = 0; mt < 4; ++mt)
            af[mt] = *(const bf16x8*)(ldsA + (size_t)(wm * 64 + mt * 16 + ml) * 32 + quad * 8);
#pragma unroll
        for (int nt = 0; nt < 4; ++nt)
            bf[nt] = *(const bf16x8*)(ldsB + (size_t)(wn * 64 + nt * 16 + ml) * 32 + quad * 8);

#pragma unroll
        for (int mt = 0; mt < 4; ++mt)
#pragma unroll
            for (int nt = 0; nt < 4; ++nt)
                acc[mt][nt] = __builtin_amdgcn_mfma_f32_16x16x32_bf16(
                    af[mt], bf[nt], acc[mt][nt], 0, 0, 0);

        __syncthreads();   // all reads done before next stage overwrites
        ga0 += 32; ga1 += 32; gb0 += 32; gb1 += 32;
    }

    // epilogue: lane holds D[m = quad*4 + r][n = ml] per 16x16 tile
    const int gm0 = bm * 128 + wm * 64;
    const int gn0 = bn * 128 + wn * 64;
#pragma unroll
    for (int nt = 0; nt < 4; ++nt) {
        const int gn = gn0 + nt * 16 + ml;
        const float bv = bias[gn];
#pragma unroll
        for (int mt = 0; mt < 4; ++mt) {
            const int gm = gm0 + mt * 16 + quad * 4;
#pragma unroll
            for (int r = 0; r < 4; ++r)
                C[(size_t)(gm + r) * OUT_CH + gn] = acc[mt][nt][r] + bv;
        }
    }
}

extern "C" void kernel_launch(void* const* d_in, const int* in_sizes, int n_in,
                              void* d_out, int out_size, void* d_ws, size_t ws_size,
                              hipStream_t stream) {
    const float* x    = (const float*)d_in[0];
    const float* sw   = (const float*)d_in[1];
    const float* bias = (const float*)d_in[2];
    const int*   rows = (const int*)d_in[3];
    const int*   cols = (const int*)d_in[4];
    const int    nnz  = in_sizes[1];

    char* base = (char*)d_ws;
    unsigned short* W  = (unsigned short*)base;                                   // 32 MB
    int*            idx = (int*)(base + (size_t)OUT_CH * IN_CH * 2);              // 64 MB @ +32MB
    unsigned short* xb  = (unsigned short*)(base + (size_t)OUT_CH * IN_CH * 2);   // 128 MB @ +32MB (reuses idx region AFTER scatter)

    // 16.7M cells / 8 per thread
    hipLaunchKernelGGL(init_ws, dim3(8192), dim3(256), 0, stream, W, idx);
    hipLaunchKernelGGL(scatter_max, dim3((nnz + 255) / 256), dim3(256), 0, stream,
                       rows, cols, idx, nnz);
    hipLaunchKernelGGL(scatter_write, dim3((nnz + 255) / 256), dim3(256), 0, stream,
                       rows, cols, sw, idx, W, nnz);
    // 67108864 / 8 / 256 = 32768 blocks
    hipLaunchKernelGGL(convert_x, dim3(32768), dim3(256), 0, stream, x, xb);
    // (16384/128) * (4096/128) = 4096 blocks
    hipLaunchKernelGGL(gemm_bt, dim3(4096), dim3(256), 0, stream, xb, W, bias, (float*)d_out);
}

// Round 2
// 1110.955 us; speedup vs baseline: 1.0114x; 1.0114x over previous
//
#include <hip/hip_runtime.h>

#define IN_CH 4096
#define OUT_CH 4096
#define BATCH 16384

typedef __attribute__((ext_vector_type(8))) short bf16x8;
typedef __attribute__((ext_vector_type(4))) float f32x4;
typedef __attribute__((ext_vector_type(8))) unsigned short us8;

__device__ __forceinline__ unsigned short f2bf(float f) {
    union { float f; unsigned int u; } v; v.f = f;
    unsigned int u = v.u;
    unsigned int r = (u + 0x7fffu + ((u >> 16) & 1u)) >> 16;  // RNE
    return (unsigned short)r;
}

// ---- pass 1: last-occurrence-wins via atomicMax of (i+1); 0 = empty ----
__global__ void scatter_max(const int* __restrict__ rows, const int* __restrict__ cols,
                            int* __restrict__ idx, int nnz) {
    int i = blockIdx.x * blockDim.x + threadIdx.x;
    if (i < nnz) {
        atomicMax(&idx[(size_t)rows[i] * IN_CH + cols[i]], i + 1);
    }
}

// ---- pass 2: winner writes its (bf16) weight ----
__global__ void scatter_write(const int* __restrict__ rows, const int* __restrict__ cols,
                              const float* __restrict__ w, const int* __restrict__ idx,
                              unsigned short* __restrict__ W, int nnz) {
    int i = blockIdx.x * blockDim.x + threadIdx.x;
    if (i < nnz) {
        size_t cell = (size_t)rows[i] * IN_CH + cols[i];
        if (idx[cell] == i + 1) W[cell] = f2bf(w[i]);
    }
}

// ---- x f32 -> bf16, 8 elems/thread ----
__global__ void convert_x(const float* __restrict__ x, unsigned short* __restrict__ xb) {
    size_t i = ((size_t)blockIdx.x * blockDim.x + threadIdx.x) * 8;
    float4 f0 = *(const float4*)(x + i);
    float4 f1 = *(const float4*)(x + i + 4);
    us8 o;
    o[0] = f2bf(f0.x); o[1] = f2bf(f0.y); o[2] = f2bf(f0.z); o[3] = f2bf(f0.w);
    o[4] = f2bf(f1.x); o[5] = f2bf(f1.y); o[6] = f2bf(f1.z); o[7] = f2bf(f1.w);
    *(us8*)(xb + i) = o;
}

__device__ __forceinline__ void gl_lds16(const unsigned short* g, unsigned short* l) {
    __builtin_amdgcn_global_load_lds(
        (const __attribute__((address_space(1))) unsigned int*)g,
        (__attribute__((address_space(3))) unsigned int*)l,
        16, 0, 0);
}

// ---- C[M,N] = A[M,K] * B[N,K]^T + bias ; 128x128 block tile, BK=32,
//      4 waves in 2x2, each wave 4x4 grid of 16x16x32 MFMA.
//      LDS XOR-swizzle: logical chunk (row r, k-chunk q) stored at physical
//      chunk r*4 + (q ^ ((r>>1)&3)) -> ds_read_b128 conflict-free per 8-lane
//      phase (bank-group (ml&1)*4 + quad^((ml>>1)&3) is a bijection). ----
__global__ __launch_bounds__(256) void gemm_bt(
    const unsigned short* __restrict__ A,   // x_bf16 [BATCH][IN_CH]
    const unsigned short* __restrict__ B,   // W_bf16 [OUT_CH][IN_CH]
    const float* __restrict__ bias,         // [OUT_CH]
    float* __restrict__ C)                  // [BATCH][OUT_CH]
{
    __shared__ unsigned short lds[8192];    // A tile [0,4096), B tile [4096,8192)
    const int tid  = threadIdx.x;
    const int wave = tid >> 6;
    const int lane = tid & 63;
    const int bm = blockIdx.x >> 5;         // 0..127  (M/128)
    const int bn = blockIdx.x & 31;         // 0..31   (N/128)
    const int wm = wave & 1;
    const int wn = wave >> 1;
    const int ml   = lane & 15;             // m (A) / n (B) within 16
    const int quad = lane >> 4;             // 0..3
    // staging: lane l covers logical (srow, c); source chunk swizzled
    const int srow = lane >> 2;
    const int c    = lane & 3;
    const int scol = (c ^ ((srow >> 1) & 3)) * 8;   // swizzled k-offset (elems)

    const int seg0 = wave * 2;
    const unsigned short* ga0 = A + (size_t)(bm * 128 + seg0 * 16 + srow) * IN_CH + scol;
    const unsigned short* ga1 = ga0 + 16 * IN_CH;
    const unsigned short* gb0 = B + (size_t)(bn * 128 + seg0 * 16 + srow) * IN_CH + scol;
    const unsigned short* gb1 = gb0 + 16 * IN_CH;
    unsigned short* la0 = lds + seg0 * 512;
    unsigned short* la1 = la0 + 512;
    unsigned short* lb0 = lds + 4096 + seg0 * 512;
    unsigned short* lb1 = lb0 + 512;

    f32x4 acc[4][4];
#pragma unroll
    for (int i = 0; i < 4; ++i)
#pragma unroll
        for (int j = 0; j < 4; ++j) acc[i][j] = (f32x4){0.f, 0.f, 0.f, 0.f};

    const unsigned short* ldsA = lds;
    const unsigned short* ldsB = lds + 4096;
    const int swk = (quad ^ ((ml >> 1) & 3)) * 8;   // swizzled k-chunk offset (elems)

    for (int kt = 0; kt < IN_CH / 32; ++kt) {
        gl_lds16(ga0, la0);
        gl_lds16(ga1, la1);
        gl_lds16(gb0, lb0);
        gl_lds16(gb1, lb1);
        __syncthreads();   // drains vmcnt -> LDS writes visible

        bf16x8 af[4], bf[4];
#pragma unroll
        for (int mt = 0; mt < 4; ++mt)
            af[mt] = *(const bf16x8*)(ldsA + (size_t)(wm * 64 + mt * 16 + ml) * 32 + swk);
#pragma unroll
        for (int nt = 0; nt < 4; ++nt)
            bf[nt] = *(const bf16x8*)(ldsB + (size_t)(wn * 64 + nt * 16 + ml) * 32 + swk);

#pragma unroll
        for (int mt = 0; mt < 4; ++mt)
#pragma unroll
            for (int nt = 0; nt < 4; ++nt)
                acc[mt][nt] = __builtin_amdgcn_mfma_f32_16x16x32_bf16(
                    af[mt], bf[nt], acc[mt][nt], 0, 0, 0);

        __syncthreads();   // all reads done before next stage overwrites
        ga0 += 32; ga1 += 32; gb0 += 32; gb1 += 32;
    }

    // epilogue: lane holds D[m = quad*4 + r][n = ml] per 16x16 tile
    const int gm0 = bm * 128 + wm * 64;
    const int gn0 = bn * 128 + wn * 64;
#pragma unroll
    for (int nt = 0; nt < 4; ++nt) {
        const int gn = gn0 + nt * 16 + ml;
        const float bv = bias[gn];
#pragma unroll
        for (int mt = 0; mt < 4; ++mt) {
            const int gm = gm0 + mt * 16 + quad * 4;
#pragma unroll
            for (int r = 0; r < 4; ++r)
                C[(size_t)(gm + r) * OUT_CH + gn] = acc[mt][nt][r] + bv;
        }
    }
}

extern "C" void kernel_launch(void* const* d_in, const int* in_sizes, int n_in,
                              void* d_out, int out_size, void* d_ws, size_t ws_size,
                              hipStream_t stream) {
    const float* x    = (const float*)d_in[0];
    const float* sw   = (const float*)d_in[1];
    const float* bias = (const float*)d_in[2];
    const int*   rows = (const int*)d_in[3];
    const int*   cols = (const int*)d_in[4];
    const int    nnz  = in_sizes[1];

    char* base = (char*)d_ws;
    unsigned short* W  = (unsigned short*)base;                                   // [0, 32MB)
    int*            idx = (int*)(base + (size_t)OUT_CH * IN_CH * 2);              // [32MB, 96MB)
    unsigned short* xb  = (unsigned short*)(base + (size_t)OUT_CH * IN_CH * 2);   // [32MB, 160MB) — overwrites idx AFTER scatter

    // W = 0 (bf16 zero == 0x0000) and idx = 0 (empty sentinel) in one memset
    hipMemsetAsync(d_ws, 0, (size_t)OUT_CH * IN_CH * 2 + (size_t)OUT_CH * IN_CH * 4, stream);
    hipLaunchKernelGGL(scatter_max, dim3((nnz + 255) / 256), dim3(256), 0, stream,
                       rows, cols, idx, nnz);
    hipLaunchKernelGGL(scatter_write, dim3((nnz + 255) / 256), dim3(256), 0, stream,
                       rows, cols, sw, idx, W, nnz);
    hipLaunchKernelGGL(convert_x, dim3(32768), dim3(256), 0, stream, x, xb);
    hipLaunchKernelGGL(gemm_bt, dim3(4096), dim3(256), 0, stream, xb, W, bias, (float*)d_out);
}